// Round 9
// baseline (413.257 us; speedup 1.0000x reference)
//
#include <hip/hip_runtime.h>
#include <math.h>

#define S_LEN 4096
#define D_MODEL 2048
#define N_HEADS 16
#define N_KV 4
#define HEAD_DIM 128
#define KV_D 512
#define QKV_N 3072   // fused QKV projection width; Q/K row stride
#define SM_SHIFT 18.0f  // fixed softmax shift (log2 domain); exact identity

typedef short bf16x8 __attribute__((ext_vector_type(8)));
typedef float f32x4 __attribute__((ext_vector_type(4)));

#if __has_builtin(__builtin_amdgcn_exp2f)
#define EXP2(x) __builtin_amdgcn_exp2f(x)
#else
#define EXP2(x) exp2f(x)
#endif

// raw barrier with compiler memory ordering (no implicit full waitcnt drain)
#define SBAR() asm volatile("s_barrier" ::: "memory")
#define VMCNT(n) asm volatile("s_waitcnt vmcnt(" #n ")" ::: "memory")

static __device__ __forceinline__ float b2f(unsigned short h) {
  return __uint_as_float(((unsigned int)h) << 16);
}
// HW packed f32->bf16 (RNE): lo half = cvt(a), hi half = cvt(b). 1 instr vs ~7.
static __device__ __forceinline__ unsigned int cvt_pk_bf16(float a, float b) {
  unsigned int r;
  asm("v_cvt_pk_bf16_f32 %0, %1, %2" : "=v"(r) : "v"(a), "v"(b));
  return r;
}
// scalar f32->bf16 via the same HW op (RNE; identical numerics to manual RNE)
static __device__ __forceinline__ unsigned short f2b(float f) {
  return (unsigned short)cvt_pk_bf16(f, f);
}

// async 16B global -> LDS (wave-uniform base + lane*16 ordering)
static __device__ __forceinline__ void gload_lds16(const unsigned short* g,
                                                   unsigned short* l) {
  __builtin_amdgcn_global_load_lds(
      (const __attribute__((address_space(1))) void*)g,
      (__attribute__((address_space(3))) void*)l, 16, 0, 0);
}

// ---------------------------------------------------------------------------
// prep: blocks [0,4096) convert X fp32->bf16; remaining blocks transpose the
// four weight matrices into bf16 W^T form (Wq/Wk/Wv stacked [3072][2048]).
// ---------------------------------------------------------------------------
__global__ __launch_bounds__(256) void prep_kernel(
    const float* __restrict__ X, const float* __restrict__ Wq,
    const float* __restrict__ Wk, const float* __restrict__ Wv,
    const float* __restrict__ Wo, unsigned short* __restrict__ Xb,
    unsigned short* __restrict__ Wqkv, unsigned short* __restrict__ WoT) {
  __shared__ float tile[32][33];
  const int b = blockIdx.x, t = threadIdx.x;
  if (b < 4096) {  // convx: 2048 elems per block
    int i = b * 2048 + t * 8;
    float4 a = *(const float4*)(X + i);
    float4 v = *(const float4*)(X + i + 4);
    unsigned int tmp[4] = {cvt_pk_bf16(a.x, a.y), cvt_pk_bf16(a.z, a.w),
                           cvt_pk_bf16(v.x, v.y), cvt_pk_bf16(v.z, v.w)};
    *(uint4*)&Xb[i] = *(uint4*)tmp;
    return;
  }
  int id = b - 4096;
  const float* src;
  unsigned short* dst;
  int N, tc, rowOff;
  if (id < 4096) { src = Wq; dst = Wqkv; N = 2048; tc = 64; rowOff = 0; }
  else if (id < 5120) { id -= 4096; src = Wk; dst = Wqkv; N = 512; tc = 16; rowOff = 2048; }
  else if (id < 6144) { id -= 5120; src = Wv; dst = Wqkv; N = 512; tc = 16; rowOff = 2560; }
  else { id -= 6144; src = Wo; dst = WoT; N = 2048; tc = 64; rowOff = 0; }
  const int c0 = (id % tc) * 32, r0 = (id / tc) * 32;
  const int col = t & 31, rb = t >> 5;
#pragma unroll
  for (int i = 0; i < 4; i++)
    tile[rb + i * 8][col] = src[(size_t)(r0 + rb + i * 8) * N + c0 + col];
  __syncthreads();
#pragma unroll
  for (int i = 0; i < 4; i++)
    dst[(size_t)(rowOff + c0 + rb + i * 8) * 2048 + r0 + col] =
        f2b(tile[col][rb + i * 8]);
}

// ---------------------------------------------------------------------------
// bf16 MFMA GEMM (m97 structure + T1 XCD swizzle; R9: BK 32->64).
// C(MxN) = A(MxK) @ Bt(NxK)^T. 128x128 tile, BK=64, 256 thr = 4 waves,
// global_load_lds staging, 32KB LDS single-buffered. Halves the
// barrier-drain count vs BK=32 (the known ~20% stall of this structure).
// 128B row stride would be a 32-way bank conflict -> chunk^(row&7)
// both-sides involution (pre-swizzled global source + swizzled ds_read).
// kk-outer fragment loads keep live frag regs at the BK=32 level.
// ---------------------------------------------------------------------------
__global__ __launch_bounds__(256) void bgemm_kernel(
    const unsigned short* __restrict__ A, const unsigned short* __restrict__ Bt,
    void* __restrict__ C, int M, int N, int K, int bf16_out) {
  __shared__ unsigned short As[128 * 64];
  __shared__ unsigned short Bs[128 * 64];

  const int t = threadIdx.x;
  const int w = t >> 6, l = t & 63;
  const int quad = l >> 4, lx = l & 15, lx7 = lx & 7;

  // T1 XCD swizzle (bijective: nwg % 8 == 0 for both call sites)
  const int nwg = gridDim.x * gridDim.y;
  const int orig = blockIdx.y * gridDim.x + blockIdx.x;
  const int swz = (orig & 7) * (nwg >> 3) + (orig >> 3);
  const int bx = swz % gridDim.x, by = swz / gridDim.x;
  const int row0 = by * 128, col0 = bx * 128;
  const int wr = (w >> 1) * 64, wc = (w & 1) * 64;

  // staging: 1024 chunks (16B) per matrix, 4 per thread; source pre-swizzled
  // by the involution chunk c -> c^(r&7) so swizzled ds_reads see row r's
  // true chunk c.
  const unsigned short* agp[4];
  const unsigned short* bgp[4];
#pragma unroll
  for (int j = 0; j < 4; j++) {
    int ch = j * 256 + t;
    int r = ch >> 3, c = ch & 7;
    agp[j] = A + (size_t)(row0 + r) * K + ((c ^ (r & 7)) << 3);
    bgp[j] = Bt + (size_t)(col0 + r) * K + ((c ^ (r & 7)) << 3);
  }

  f32x4 acc[4][4];
#pragma unroll
  for (int mt = 0; mt < 4; mt++)
#pragma unroll
    for (int nt = 0; nt < 4; nt++) acc[mt][nt] = (f32x4){0.f, 0.f, 0.f, 0.f};

  for (int kt = 0; kt < K; kt += 64) {
    __syncthreads();
#pragma unroll
    for (int j = 0; j < 4; j++) {
      int ch = j * 256 + t;
      gload_lds16(agp[j] + kt, &As[ch * 8]);
      gload_lds16(bgp[j] + kt, &Bs[ch * 8]);
    }
    __syncthreads();

#pragma unroll
    for (int kk = 0; kk < 2; kk++) {
      bf16x8 af[4], bfr[4];
#pragma unroll
      for (int mt = 0; mt < 4; mt++)
        af[mt] = *(const bf16x8*)&As[(wr + mt * 16 + lx) * 64 +
                                     (((kk * 4 + quad) ^ lx7) << 3)];
#pragma unroll
      for (int nt = 0; nt < 4; nt++)
        bfr[nt] = *(const bf16x8*)&Bs[(wc + nt * 16 + lx) * 64 +
                                      (((kk * 4 + quad) ^ lx7) << 3)];
#pragma unroll
      for (int mt = 0; mt < 4; mt++)
#pragma unroll
        for (int nt = 0; nt < 4; nt++)
          acc[mt][nt] = __builtin_amdgcn_mfma_f32_16x16x32_bf16(
              af[mt], bfr[nt], acc[mt][nt], 0, 0, 0);
    }
  }

  if (bf16_out) {
    unsigned short* Cp = (unsigned short*)C;
#pragma unroll
    for (int mt = 0; mt < 4; mt++)
#pragma unroll
      for (int nt = 0; nt < 4; nt++)
#pragma unroll
        for (int r = 0; r < 4; r++) {
          int row = row0 + wr + mt * 16 + quad * 4 + r;
          int col = col0 + wc + nt * 16 + lx;
          Cp[(size_t)row * N + col] = f2b(acc[mt][nt][r]);
        }
  } else {
    float* Cp = (float*)C;
#pragma unroll
    for (int mt = 0; mt < 4; mt++)
#pragma unroll
      for (int nt = 0; nt < 4; nt++)
#pragma unroll
        for (int r = 0; r < 4; r++) {
          int row = row0 + wr + mt * 16 + quad * 4 + r;
          int col = col0 + wc + nt * 16 + lx;
          Cp[(size_t)row * N + col] = acc[mt][nt][r];
        }
  }
}

// ---------------------------------------------------------------------------
// Merged RoPE + V-transpose (independent column ranges of QKV; one launch).
// Blocks [0, 20480): RoPE in place on QKV (row stride 3072). Q cols [0,2048)
// get the combined scale log2(e)/sqrt(HD); K cols [2048,2560) unscaled.
// Blocks [20480, 22528): transpose V (cols [2560,3072)) -> Vt (512 x S).
// ---------------------------------------------------------------------------
__global__ __launch_bounds__(256) void ropev_kernel(
    unsigned short* __restrict__ QKV, unsigned short* __restrict__ Vt) {
  const int t = threadIdx.x;
  if (blockIdx.x < 20480) {
    int id = blockIdx.x * 256 + t;
    int d = id & 63;
    int rem = id >> 6;
    int head = rem % 20;
    int s = rem / 20;
    unsigned short* p;
    float scale;
    if (head < N_HEADS) {
      p = QKV + (size_t)s * QKV_N + head * HEAD_DIM;
      scale = 0.12753139187f;  // log2(e) / sqrt(128)
    } else {
      p = QKV + (size_t)s * QKV_N + 2048 + (head - N_HEADS) * HEAD_DIM;
      scale = 1.0f;
    }
    float inv = exp2f(-(float)d * (13.287712379549449f / 64.0f));
    float ang = (float)s * inv;
    float sn, c;
    sincosf(ang, &sn, &c);
    float xr = b2f(p[d]), xi = b2f(p[d + 64]);
    p[d] = f2b((xr * c - xi * sn) * scale);
    p[d + 64] = f2b((xr * sn + xi * c) * scale);
    return;
  }
  __shared__ unsigned short tile[32][33];
  const unsigned short* Vb = QKV + 2560;
  int id = blockIdx.x - 20480;
  const int c0 = (id & 15) * 32;   // 512/32 = 16 column tiles
  const int s0 = (id >> 4) * 32;
  const int col = t & 31, rbase = t >> 5;
#pragma unroll
  for (int i = 0; i < 4; i++) {
    int row = rbase + i * 8;
    tile[row][col] = Vb[(size_t)(s0 + row) * QKV_N + c0 + col];
  }
  __syncthreads();
#pragma unroll
  for (int i = 0; i < 4; i++) {
    int row = rbase + i * 8;
    Vt[(size_t)(c0 + row) * S_LEN + s0 + col] = tile[col][row];
  }
}

// ---------------------------------------------------------------------------
// Flash attention, transposed-score form, FIXED-SHIFT softmax.
// R9: BQ 128->64 (16 q/wave). R8 showed occupancy pinned at 2 blocks/CU by
// GRID SIZE (512 blocks / 256 CUs), not capacity. Halving BQ: grid
// (64,16)=1024 blocks = 4/CU; LDS Ks16+Vs16+Pt(4x2)=40KB -> exactly 4
// blocks/CU = 16 waves/CU (2x R8). Per-wave state halves (qf 16, oacc 32
// acc) -> ~100 unified regs, fits the (256,4) 128-cap with margin (R2's
// failure was demand 176 > 128). Staging traffic doubles but is L2-resident
// (R7 kvh-per-XCD swizzle): ~1.9 TB/s per XCD vs 4.3 ceiling.
// Same verified 3-barrier single-buffer schedule as R8.
// ---------------------------------------------------------------------------
__global__ __launch_bounds__(256, 4) void attn_kernel(
    const unsigned short* __restrict__ Qb, const unsigned short* __restrict__ Kb,
    const unsigned short* __restrict__ Vt, unsigned short* __restrict__ Ob) {
  __shared__ unsigned short Ks[64 * 128];   // [krow][d], chunk-swizzled
  __shared__ unsigned short Vs[128 * 64];   // [d][krow], chunk-swizzled
  __shared__ unsigned short Pt[4][16 * 64]; // per-wave P^T [q][k], swizzled

  const int t = threadIdx.x;
  const int wave = t >> 6;
  const int lane = t & 63;
  const int quad = lane >> 4;
  const int lx = lane & 15;
  const int lx7 = lx & 7;

  // T1 XCD swizzle: grid (64,16) = 1024; XCD x gets ids [128x,128x+128)
  // = heads [2x,2x+2) -> one kvh group per XCD (2MB, L2-resident).
  const int orig = blockIdx.y * gridDim.x + blockIdx.x;
  const int swz = (orig & 7) * 128 + (orig >> 3);
  const int qt = swz & 63;   // 0..63
  const int h = swz >> 6;    // 0..15
  const int kvh = h >> 2;

  const unsigned short* Kg = Kb + kvh * HEAD_DIM;              // stride QKV_N
  const unsigned short* Vg = Vt + (size_t)(kvh * HEAD_DIM) * S_LEN;

  // Q fragments (whole kernel in registers): B-operand [n=lx][k=quad*8+j]
  const unsigned short* Qg =
      Qb + (size_t)(qt * 64 + wave * 16) * QKV_N + h * HEAD_DIM;
  bf16x8 qf[4];
#pragma unroll
  for (int ks = 0; ks < 4; ks++)
    qf[ks] = *(const bf16x8*)(Qg + (size_t)lx * QKV_N + (quad << 3) + (ks << 5));

  f32x4 oacc[8];
#pragma unroll
  for (int dt = 0; dt < 8; dt++) oacc[dt] = (f32x4){0.f, 0.f, 0.f, 0.f};
  float l_st = 0.f;

  // K tile: 64 rows x 16 chunks; slot(r,c) holds global chunk (r, c^(r&7)).
  // V^T tile: 128 rows x 8 chunks; same self-inverse XOR swizzle.
  const unsigned short* kgp[4];
  const unsigned short* vgp[4];
#pragma unroll
  for (int j = 0; j < 4; j++) {
    int ch = (j * 4 + wave) * 64 + lane;
    int r = ch >> 4, c = ch & 15;
    kgp[j] = Kg + (size_t)r * QKV_N + ((c ^ (r & 7)) << 3);
    int d = ch >> 3, c2 = ch & 7;
    vgp[j] = Vg + (size_t)d * S_LEN + ((c2 ^ (d & 7)) << 3);
  }

  auto stageK = [&](int kt) {
#pragma unroll
    for (int j = 0; j < 4; j++) {  // 4 * 4 waves * 64 lanes = 1024 chunks
      int ch = (j * 4 + wave) * 64 + lane;
      gload_lds16(kgp[j] + (size_t)kt * (64 * QKV_N), &Ks[ch * 8]);
    }
  };
  auto stageV = [&](int kt) {
#pragma unroll
    for (int j = 0; j < 4; j++) {
      int ch = (j * 4 + wave) * 64 + lane;
      gload_lds16(vgp[j] + kt * 64, &Vs[ch * 8]);
    }
  };

  stageK(0);
  stageV(0);

  for (int kt = 0; kt < S_LEN / 64; kt++) {
    VMCNT(4);   // own K(kt) landed (V(kt) may still be in flight)
    SBAR();     // all waves' K(kt) visible

    // ---- S^T = K @ Q^T fused with exp2/store; acc seeded with -SM_SHIFT so
    // no per-element subtract: k = ksub*16+quad*4+r, q = lx
#pragma unroll
    for (int ksub = 0; ksub < 4; ksub++) {
      bf16x8 kf[4];
#pragma unroll
      for (int ks = 0; ks < 4; ks++)
        kf[ks] = *(const bf16x8*)&Ks[(ksub * 16 + lx) * 128 +
                                     (((ks * 4 + quad) ^ lx7) << 3)];
      f32x4 a = (f32x4){-SM_SHIFT, -SM_SHIFT, -SM_SHIFT, -SM_SHIFT};
      __builtin_amdgcn_s_setprio(1);
#pragma unroll
      for (int ks = 0; ks < 4; ks++)
        a = __builtin_amdgcn_mfma_f32_16x16x32_bf16(kf[ks], qf[ks], a, 0, 0, 0);
      __builtin_amdgcn_s_setprio(0);
      float p0 = EXP2(a[0]);
      float p1 = EXP2(a[1]);
      float p2 = EXP2(a[2]);
      float p3 = EXP2(a[3]);
      l_st += (p0 + p1) + (p2 + p3);
      // P^T[q][k]: k = ksub*16+quad*4 (+r); chunk 2ksub+(quad>>1) ^ lx7
      *(uint2*)&Pt[wave][lx * 64 + (((2 * ksub + (quad >> 1)) ^ lx7) << 3) +
                         ((quad & 1) << 2)] =
          make_uint2(cvt_pk_bf16(p0, p1), cvt_pk_bf16(p2, p3));
    }

    // ---- V(kt) visible + all waves' Ks reads retired -> K buffer free ----
    VMCNT(0);
    SBAR();
    if (kt + 1 < S_LEN / 64) stageK(kt + 1);  // hides under PV

    // ---- O^T += V^T @ P^T (Pt wave-local: lgkm wait only) ----
#pragma unroll
    for (int st = 0; st < 2; st++) {
      const int pc = ((st * 4 + quad) ^ lx7) << 3;
      bf16x8 pb = *(const bf16x8*)&Pt[wave][lx * 64 + pc];
      __builtin_amdgcn_s_setprio(1);
#pragma unroll
      for (int dt = 0; dt < 8; dt++) {
        bf16x8 vf = *(const bf16x8*)&Vs[(dt * 16 + lx) * 64 + pc];
        oacc[dt] = __builtin_amdgcn_mfma_f32_16x16x32_bf16(vf, pb, oacc[dt], 0, 0, 0);
      }
      __builtin_amdgcn_s_setprio(0);
    }

    // ---- all waves' Vs reads retired -> V buffer free ----
    SBAR();
    if (kt + 1 < S_LEN / 64) stageV(kt + 1);  // hides under next QK
  }

  // ---- epilogue: final cross-lane l reduce, O = (O^T)^T / l, 8B stores ----
  {
    float l = l_st;
    l += __shfl_xor(l, 16);
    l += __shfl_xor(l, 32);
    float linv = 1.0f / l;
    unsigned short* ob = Ob +
        (size_t)(qt * 64 + wave * 16 + lx) * D_MODEL + h * HEAD_DIM + quad * 4;
#pragma unroll
    for (int dt = 0; dt < 8; dt++) {
      *(uint2*)&ob[dt * 16] = make_uint2(
          cvt_pk_bf16(oacc[dt][0] * linv, oacc[dt][1] * linv),
          cvt_pk_bf16(oacc[dt][2] * linv, oacc[dt][3] * linv));
    }
  }
}

// ---------------------------------------------------------------------------
extern "C" void kernel_launch(void* const* d_in, const int* in_sizes, int n_in,
                              void* d_out, int out_size, void* d_ws,
                              size_t ws_size, hipStream_t stream) {
  const float* X = (const float*)d_in[0];   // 4096 x 2048
  const float* Wq = (const float*)d_in[1];  // 2048 x 2048
  const float* Wk = (const float*)d_in[2];  // 2048 x 512
  const float* Wv = (const float*)d_in[3];  // 2048 x 512
  const float* Wo = (const float*)d_in[4];  // 2048 x 2048
  float* out = (float*)d_out;               // 4096 x 2048

  const size_t MB = 1048576;
  char* ws = (char*)d_ws;
  unsigned short* Xb    = (unsigned short*)ws;              // 16 MB
  unsigned short* WqkvT = (unsigned short*)(ws + 16 * MB);  // 12 MB [3072][2048]
  unsigned short* WoT   = (unsigned short*)(ws + 28 * MB);  //  8 MB
  unsigned short* QKV   = (unsigned short*)(ws + 36 * MB);  // 24 MB [4096][3072]
  unsigned short* Vtr   = (unsigned short*)(ws + 60 * MB);  //  4 MB [512][4096]
  unsigned short* Ob    = (unsigned short*)(ws + 64 * MB);  // 16 MB

  dim3 blk(256);
  // prep: X conversion + all 4 weight transposes in one launch
  prep_kernel<<<14336, blk, 0, stream>>>(X, Wq, Wk, Wv, Wo, Xb, WqkvT, WoT);
  // fused QKV projection: [4096][3072] bf16 (768 wgs, %8==0 for swizzle)
  bgemm_kernel<<<dim3(QKV_N / 128, S_LEN / 128), blk, 0, stream>>>(
      Xb, WqkvT, QKV, S_LEN, QKV_N, D_MODEL, 1);
  // RoPE on Q (log2e-scaled) and K + V transpose -> Vt, one launch
  ropev_kernel<<<20480 + 2048, blk, 0, stream>>>(QKV, Vtr);
  // attention (bf16 MFMA, 16 q/wave, BQ=64, fixed-shift softmax), bf16 O
  attn_kernel<<<dim3(S_LEN / 64, N_HEADS), blk, 0, stream>>>(
      QKV, QKV + 2048, Vtr, Ob);
  // output projection (fp32 out): 512 wgs, %8==0 for swizzle
  bgemm_kernel<<<dim3(D_MODEL / 128, S_LEN / 128), blk, 0, stream>>>(
      Ob, WoT, out, S_LEN, D_MODEL, D_MODEL, 0);
}